// Round 15
// baseline (697.287 us; speedup 1.0000x reference)
//
#include <hip/hip_runtime.h>
#include <hip/hip_cooperative_groups.h>
#include <math.h>

namespace cg = cooperative_groups;

#define BB 2
#define NN 384
#define ND 8
#define CD 16
#define HH 128
#define LL 4
#define TT 100
#define TOTN (BB * NN)   // 768

__device__ __forceinline__ float silu_f(float x) {
    float s = 1.0f / (1.0f + __expf(-x));
    return x * s;
}

// ============================================================================
// PATH A: cooperative mega-kernel
// ============================================================================
struct MegaParams {
    const float *node_features, *positions, *mask, *condition, *targets, *pweights,
                *feature_noise, *position_noise;
    const int   *timesteps;
    const float *time_w1, *time_b1, *time_w2, *time_b2;
    const float *cond_w1, *cond_b1, *cond_w2, *cond_b2;
    const float *nodep_w1, *nodep_b1, *nodep_w2, *nodep_b2;
    const float *edge_w1, *edge_b1, *edge_w2, *edge_b2;
    const float *nodem_w1, *nodem_b1, *nodem_w2, *nodem_b2;
    const float *feat_w1, *feat_b1, *feat_w2, *feat_b2;
    const float *pos_w1, *pos_b1, *pos_w2, *pos_b2;
    const float *prop_w1, *prop_b1, *prop_w2, *prop_b2, *prop_w3, *prop_b3;
    float *npos, *ajA, *ajB, *gembp, *gemb, *accums, *out;
};

__global__ __launch_bounds__(256, 2) void k_mega(MegaParams P) {
    cg::grid_group grid = cg::this_grid();
    const int p   = blockIdx.x;          // 0..383
    const int n0  = p * 2;
    const int b   = (n0 >= NN) ? 1 : 0;
    const int l0  = n0 - b * NN;
    const int tid = threadIdx.x;
    const int t   = tid & 127;
    const int g   = tid >> 7;
    const int ng  = n0 + g;

    __shared__ __align__(16) float s_pos[NN * 2];
    __shared__ float s_d[2][NN];
    __shared__ float s_mask[NN];
    __shared__ __align__(16) float s_ai[2][HH];
    __shared__ __align__(16) float s_S[2][HH];
    __shared__ __align__(16) float s_st[2][HH];
    __shared__ __align__(16) float s_h[2][HH];
    __shared__ __align__(16) float s_agg[2][HH];
    __shared__ float s_red[2][2][HH];
    __shared__ float s_x[2][12];
    __shared__ float s_cond[CD];
    __shared__ float s_lfp[2];
    float* r256 = &s_red[0][0][0];

    const int ts = P.timesteps[b];
    float ab = 1.0f;
    for (int k = 0; k <= ts; ++k) {
        float beta = 1e-4f + (0.02f - 1e-4f) * ((float)k / (float)(TT - 1));
        ab *= (1.0f - beta);
    }
    const float sab = sqrtf(ab), s1ab = sqrtf(1.0f - ab);

    for (int j = tid; j < NN; j += 256) s_mask[j] = P.mask[b * NN + j];
    if (tid < CD) s_cond[tid] = P.condition[b * CD + tid];
    __syncthreads();
    {
        float m = 0.0f;
        for (int j = tid; j < NN; j += 256) m += s_mask[j];
        r256[tid] = m;
        __syncthreads();
        for (int s = 128; s > 0; s >>= 1) {
            if (tid < s) r256[tid] += r256[tid + s];
            __syncthreads();
        }
    }
    const float msum = r256[0];
    __syncthreads();
    if (l0 == 0 && tid == 0) P.accums[2 + b] = msum;
    if (p == 0 && tid < 2) P.accums[tid] = 0.0f;

    if (tid < HH) {
        const int half = HH / 2;
        float factor = logf(10000.0f) / (float)(half - 1);
        float tf = (float)ts;
        s_S[0][tid] = (tid < half) ? sinf(tf * __expf(-factor * (float)tid))
                                   : cosf(tf * __expf(-factor * (float)(tid - half)));
    }
    __syncthreads();
    {
        float pp = 0.0f;
        const int k0 = g * 64;
        for (int k = k0; k < k0 + 64; ++k) pp += s_S[0][k] * P.time_w1[k * HH + t];
        s_red[0][g][t] = pp;
    }
    __syncthreads();
    if (g == 0) s_h[0][t] = silu_f(s_red[0][0][t] + s_red[0][1][t] + P.time_b1[t]);
    __syncthreads();
    float p2 = 0.0f;
    {
        const int k0 = g * 64;
        for (int k = k0; k < k0 + 64; ++k) p2 += s_h[0][k] * P.time_w2[k * HH + t];
    }
    if (g == 0) {
        float c1 = P.cond_b1[t];
        for (int k = 0; k < CD; ++k) c1 += s_cond[k] * P.cond_w1[k * HH + t];
        s_S[0][t] = silu_f(c1);
    }
    s_red[0][g][t] = p2;
    __syncthreads();
    const float timeL2 = s_red[0][0][t] + s_red[0][1][t];
    __syncthreads();
    {
        float p4 = 0.0f;
        const int k0 = g * 64;
        for (int k = k0; k < k0 + 64; ++k) p4 += s_S[0][k] * P.cond_w2[k * HH + t];
        s_red[0][g][t] = p4;
    }
    __syncthreads();
    const float tc = timeL2 + P.time_b2[t] + s_red[0][0][t] + s_red[0][1][t] + P.cond_b2[t];
    __syncthreads();

    if (tid < 20) {
        int nn = tid / 10, c = tid % 10;
        int gnn = n0 + nn;
        float v;
        if (c < ND) {
            v = sab * P.node_features[gnn * ND + c] + s1ab * P.feature_noise[gnn * ND + c];
        } else {
            int d = c - ND;
            v = sab * P.positions[gnn * 2 + d] + s1ab * P.position_noise[gnn * 2 + d];
            P.npos[gnn * 2 + d] = v;
        }
        s_x[nn][c] = v;
    }
    __syncthreads();
    {
        float a = P.nodep_b1[t];
        #pragma unroll
        for (int k = 0; k < ND + 2; ++k) a += s_x[g][k] * P.nodep_w1[k * HH + t];
        s_h[g][t] = silu_f(a);
    }
    __syncthreads();
    {
        float pp = 0.0f;
        for (int k = 0; k < HH; k += 4) {
            float4 s = *(const float4*)&s_h[g][k];
            const float* wr = P.nodep_w2 + (size_t)k * HH + t;
            pp += s.x * wr[0] + s.y * wr[HH] + s.z * wr[2 * HH] + s.w * wr[3 * HH];
        }
        s_st[g][t] = pp + P.nodep_b2[t] + tc;
    }
    __syncthreads();
    {
        float pa = P.edge_b1[t], pj = 0.0f;
        for (int k = 0; k < HH; ++k) {
            float sk = s_st[g][k];
            pa += sk * P.edge_w1[k * HH + t];
            pj += sk * P.edge_w1[(HH + k) * HH + t];
        }
        s_ai[g][t] = pa;
        P.ajA[(size_t)ng * HH + t] = pj;
    }

    grid.sync();

    for (int i = tid; i < NN * 2; i += 256) s_pos[i] = P.npos[(size_t)b * NN * 2 + i];
    __syncthreads();
    {
        float x0 = s_pos[l0 * 2],       y0 = s_pos[l0 * 2 + 1];
        float x1 = s_pos[(l0 + 1) * 2], y1 = s_pos[(l0 + 1) * 2 + 1];
        for (int j = tid; j < NN; j += 256) {
            float px = s_pos[j * 2], py = s_pos[j * 2 + 1];
            float dx0 = x0 - px, dy0 = y0 - py;
            float dx1 = x1 - px, dy1 = y1 - py;
            s_d[0][j] = sqrtf(dx0 * dx0 + dy0 * dy0 + 1e-12f);
            s_d[1][j] = sqrtf(dx1 * dx1 + dy1 * dy1 + 1e-12f);
        }
    }
    __syncthreads();
    const float mi   = s_mask[l0 + g];
    const float deno = fmaxf(mi * msum, 1.0f);

    for (int l = 0; l < LL; ++l) {
        const float* ew1l = P.edge_w1 + (size_t)l * (2 * HH + 1) * HH;
        const float* ew2  = P.edge_w2 + (size_t)l * HH * HH;
        const float* eb2  = P.edge_b2 + (size_t)l * HH;
        const float* nw1  = P.nodem_w1 + (size_t)l * 2 * HH * HH;
        const float* nb1  = P.nodem_b1 + (size_t)l * HH;
        const float* nw2  = P.nodem_w2 + (size_t)l * HH * HH;
        const float* nb2  = P.nodem_b2 + (size_t)l * HH;
        const float wdt = ew1l[(size_t)(2 * HH) * HH + t];
        const float* ajin = (l & 1) ? P.ajB : P.ajA;

        const float av0 = s_ai[0][t], av1 = s_ai[1][t];
        float acc0 = 0.0f, acc1 = 0.0f;
        {
            const float* pa = ajin + (size_t)b * NN * HH + t;
            #pragma unroll 4
            for (int j = g; j < NN; j += 2) {
                float a = pa[(size_t)j * HH];
                float m = s_mask[j];
                acc0 = fmaf(m, silu_f(av0 + a + s_d[0][j] * wdt), acc0);
                acc1 = fmaf(m, silu_f(av1 + a + s_d[1][j] * wdt), acc1);
            }
        }
        s_red[0][g][t] = acc0;
        s_red[1][g][t] = acc1;
        __syncthreads();
        s_S[g][t] = s_red[g][0][t] + s_red[g][1][t];
        __syncthreads();

        {
            float pp = 0.0f;
            for (int k = 0; k < HH; k += 4) {
                float4 s = *(const float4*)&s_S[g][k];
                const float* wr = ew2 + (size_t)k * HH + t;
                pp += s.x * wr[0] + s.y * wr[HH] + s.z * wr[2 * HH] + s.w * wr[3 * HH];
            }
            s_agg[g][t] = mi * (pp + msum * eb2[t]) / deno;
        }
        __syncthreads();

        {
            float pp = 0.0f;
            for (int k = 0; k < HH; k += 4) {
                float4 s = *(const float4*)&s_st[g][k];
                const float* wr = nw1 + (size_t)k * HH + t;
                pp += s.x * wr[0] + s.y * wr[HH] + s.z * wr[2 * HH] + s.w * wr[3 * HH];
            }
            for (int k = 0; k < HH; k += 4) {
                float4 s = *(const float4*)&s_agg[g][k];
                const float* wr = nw1 + (size_t)(HH + k) * HH + t;
                pp += s.x * wr[0] + s.y * wr[HH] + s.z * wr[2 * HH] + s.w * wr[3 * HH];
            }
            s_h[g][t] = silu_f(pp + nb1[t]);
        }
        __syncthreads();

        {
            float pp = 0.0f;
            for (int k = 0; k < HH; k += 4) {
                float4 s = *(const float4*)&s_h[g][k];
                const float* wr = nw2 + (size_t)k * HH + t;
                pp += s.x * wr[0] + s.y * wr[HH] + s.z * wr[2 * HH] + s.w * wr[3 * HH];
            }
            s_st[g][t] = s_st[g][t] + (pp + nb2[t]) * mi;
        }
        __syncthreads();

        if (l < LL - 1) {
            const float* ew1n = P.edge_w1 + (size_t)(l + 1) * (2 * HH + 1) * HH;
            const float* eb1n = P.edge_b1 + (size_t)(l + 1) * HH;
            float pa = eb1n[t], pj = 0.0f;
            for (int k = 0; k < HH; ++k) {
                float sk = s_st[g][k];
                pa += sk * ew1n[k * HH + t];
                pj += sk * ew1n[(HH + k) * HH + t];
            }
            s_ai[g][t] = pa;
            float* ajout = (l & 1) ? P.ajA : P.ajB;
            ajout[(size_t)ng * HH + t] = pj;
            grid.sync();
        }
    }

    {
        float pf = P.feat_b1[t], pq = P.pos_b1[t];
        for (int k = 0; k < HH; k += 4) {
            float4 s = *(const float4*)&s_st[g][k];
            const float* wf = P.feat_w1 + (size_t)k * HH + t;
            const float* wp = P.pos_w1 + (size_t)k * HH + t;
            pf += s.x * wf[0] + s.y * wf[HH] + s.z * wf[2 * HH] + s.w * wf[3 * HH];
            pq += s.x * wp[0] + s.y * wp[HH] + s.z * wp[2 * HH] + s.w * wp[3 * HH];
        }
        s_S[g][t] = silu_f(pf);
        s_h[g][t] = silu_f(pq);
        if (tid == 0) { s_lfp[0] = 0.0f; s_lfp[1] = 0.0f; }
    }
    __syncthreads();
    if (t < ND) {
        float o = P.feat_b2[t];
        for (int k = 0; k < HH; ++k) o += s_S[g][k] * P.feat_w2[k * ND + t];
        float d = o - P.feature_noise[(size_t)ng * ND + t];
        atomicAdd(&s_lfp[0], mi * d * d);
    } else if (t >= 64 && t < 66) {
        int c = t - 64;
        float o = P.pos_b2[c];
        for (int k = 0; k < HH; ++k) o += s_h[g][k] * P.pos_w2[k * 2 + c];
        float d = o - P.position_noise[(size_t)ng * 2 + c];
        atomicAdd(&s_lfp[1], mi * d * d);
    }
    P.gembp[(size_t)ng * HH + t] = s_st[g][t] * mi;
    __syncthreads();
    if (tid == 0) {
        atomicAdd(&P.accums[0], s_lfp[0]);
        atomicAdd(&P.accums[1], s_lfp[1]);
    }

    grid.sync();

    if (l0 == 0) {
        float acc = 0.0f;
        const float* gp = P.gembp + (size_t)b * NN * HH + t;
        for (int r = g; r < NN; r += 2) acc += gp[(size_t)r * HH];
        s_red[0][g][t] = acc;
        __syncthreads();
        if (g == 0) P.gemb[b * HH + t] = (s_red[0][0][t] + s_red[0][1][t]) / fmaxf(msum, 1.0f);
    }

    grid.sync();

    if (p == 0) {
        s_S[g][t] = P.gemb[g * HH + t];
        if (tid == 0) s_lfp[0] = 0.0f;
        __syncthreads();
        float a = P.prop_b1[t];
        for (int k = 0; k < HH; ++k) a += s_S[g][k] * P.prop_w1[k * HH + t];
        s_h[g][t] = silu_f(a);
        __syncthreads();
        if (t < 64) {
            float a2 = P.prop_b2[t];
            for (int k = 0; k < HH; ++k) a2 += s_h[g][k] * P.prop_w2[k * 64 + t];
            s_agg[g][t] = silu_f(a2);
        }
        __syncthreads();
        if (t < 4) {
            float o = P.prop_b3[t];
            for (int k = 0; k < 64; ++k) o += s_agg[g][k] * P.prop_w3[k * 4 + t];
            float d = o - P.targets[g * 4 + t];
            atomicAdd(&s_lfp[0], d * d * P.pweights[t]);
        }
        __syncthreads();
        if (tid == 0) {
            float msumt = fmaxf(P.accums[2] + P.accums[3], 1.0f);
            float noise = (P.accums[0] + P.accums[1]) / msumt;
            float prop  = s_lfp[0] / (float)(BB * 4);
            P.out[0] = noise;
            P.out[1] = prop;
            P.out[2] = noise + prop;
        }
    }
}

// ============================================================================
// PATH B: fallback multi-kernel (round-8 structure, measured correct @320us)
// ============================================================================
__global__ void k_prep(const float* __restrict__ mask, const float* __restrict__ condition,
                       const int* __restrict__ timesteps,
                       const float* __restrict__ time_w1, const float* __restrict__ time_b1,
                       const float* __restrict__ time_w2, const float* __restrict__ time_b2,
                       const float* __restrict__ cond_w1, const float* __restrict__ cond_b1,
                       const float* __restrict__ cond_w2, const float* __restrict__ cond_b2,
                       float* __restrict__ tc, float* __restrict__ scal, float* __restrict__ accums) {
    int b = blockIdx.x;
    int t = threadIdx.x;
    __shared__ float sh[HH];
    __shared__ float sh2[HH];
    __shared__ float shc[CD];
    __shared__ float red[HH];

    if (b == 0 && t < 2) accums[t] = 0.0f;

    int ts = timesteps[b];
    float ab = 1.0f;
    for (int k = 0; k <= ts; ++k) {
        float beta = 1e-4f + (0.02f - 1e-4f) * ((float)k / (float)(TT - 1));
        ab *= (1.0f - beta);
    }
    if (t == 0) {
        scal[b * 4 + 0] = sqrtf(ab);
        scal[b * 4 + 1] = sqrtf(1.0f - ab);
    }
    float m = 0.0f;
    for (int j = t; j < NN; j += HH) m += mask[b * NN + j];
    red[t] = m;
    __syncthreads();
    for (int s = 64; s > 0; s >>= 1) {
        if (t < s) red[t] += red[t + s];
        __syncthreads();
    }
    if (t == 0) scal[b * 4 + 2] = red[0];

    const int half = HH / 2;
    float factor = logf(10000.0f) / (float)(half - 1);
    float tf = (float)ts;
    float temb;
    if (t < half) temb = sinf(tf * __expf(-factor * (float)t));
    else          temb = cosf(tf * __expf(-factor * (float)(t - half)));
    sh[t] = temb;
    if (t < CD) shc[t] = condition[b * CD + t];
    __syncthreads();

    float acc = time_b1[t];
    for (int k = 0; k < HH; ++k) acc += sh[k] * time_w1[k * HH + t];
    sh2[t] = silu_f(acc);
    __syncthreads();
    float acc2 = time_b2[t];
    for (int k = 0; k < HH; ++k) acc2 += sh2[k] * time_w2[k * HH + t];
    float acc3 = cond_b1[t];
    for (int k = 0; k < CD; ++k) acc3 += shc[k] * cond_w1[k * HH + t];
    __syncthreads();
    sh[t] = silu_f(acc3);
    __syncthreads();
    float acc4 = cond_b2[t];
    for (int k = 0; k < HH; ++k) acc4 += sh[k] * cond_w2[k * HH + t];

    tc[b * HH + t] = acc2 + acc4;
}

__global__ __launch_bounds__(256) void k_node_init(
    const float* __restrict__ node_features, const float* __restrict__ positions,
    const float* __restrict__ feature_noise, const float* __restrict__ position_noise,
    const float* __restrict__ nodep_w1, const float* __restrict__ nodep_b1,
    const float* __restrict__ nodep_w2, const float* __restrict__ nodep_b2,
    const float* __restrict__ tc, const float* __restrict__ scal,
    const float* __restrict__ ew1_0, const float* __restrict__ eb1_0,
    float* __restrict__ state, float* __restrict__ npos,
    float* __restrict__ ai0, float* __restrict__ aj0) {
    const int tid = threadIdx.x;
    const int t = tid & 127;
    const int g = tid >> 7;
    const int b0 = blockIdx.x * 4;
    const int b = b0 / NN;

    __shared__ __align__(16) float x[4][12];
    __shared__ __align__(16) float sh1[4][HH];
    __shared__ __align__(16) float sst[4][HH];
    __shared__ float sred[4][2][HH];

    if (tid < 40) {
        int n = tid / 10, c = tid % 10;
        int gn = b0 + n;
        float sab = scal[b * 4 + 0], s1ab = scal[b * 4 + 1];
        float v;
        if (c < ND) {
            v = sab * node_features[gn * ND + c] + s1ab * feature_noise[gn * ND + c];
        } else {
            int d = c - ND;
            v = sab * positions[gn * 2 + d] + s1ab * position_noise[gn * 2 + d];
            npos[gn * 2 + d] = v;
        }
        x[n][c] = v;
    }
    __syncthreads();

    for (int n = 2 * g; n <= 2 * g + 1; ++n) {
        float a = nodep_b1[t];
        #pragma unroll
        for (int k = 0; k < ND + 2; ++k) a += x[n][k] * nodep_w1[k * HH + t];
        sh1[n][t] = silu_f(a);
    }
    __syncthreads();

    {
        float a0 = 0, a1 = 0, a2 = 0, a3 = 0;
        const int k0 = g * 64;
        const float* wr = nodep_w2 + (size_t)k0 * HH + t;
        for (int kk = 0; kk < 64; kk += 4) {
            float w0 = wr[(kk + 0) * HH], w1 = wr[(kk + 1) * HH];
            float w2 = wr[(kk + 2) * HH], w3 = wr[(kk + 3) * HH];
            float4 s;
            s = *(const float4*)&sh1[0][k0 + kk]; a0 += s.x * w0 + s.y * w1 + s.z * w2 + s.w * w3;
            s = *(const float4*)&sh1[1][k0 + kk]; a1 += s.x * w0 + s.y * w1 + s.z * w2 + s.w * w3;
            s = *(const float4*)&sh1[2][k0 + kk]; a2 += s.x * w0 + s.y * w1 + s.z * w2 + s.w * w3;
            s = *(const float4*)&sh1[3][k0 + kk]; a3 += s.x * w0 + s.y * w1 + s.z * w2 + s.w * w3;
        }
        sred[0][g][t] = a0; sred[1][g][t] = a1; sred[2][g][t] = a2; sred[3][g][t] = a3;
    }
    __syncthreads();
    {
        float tcv = nodep_b2[t] + tc[b * HH + t];
        for (int n = 2 * g; n <= 2 * g + 1; ++n) {
            float st = sred[n][0][t] + sred[n][1][t] + tcv;
            state[(size_t)(b0 + n) * HH + t] = st;
            sst[n][t] = st;
        }
    }
    __syncthreads();

    {
        float a0 = 0, a1 = 0, a2 = 0, a3 = 0;
        const int k0 = g * 64;
        const float* wr = ew1_0 + (size_t)k0 * HH + t;
        for (int kk = 0; kk < 64; kk += 4) {
            float w0 = wr[(kk + 0) * HH], w1 = wr[(kk + 1) * HH];
            float w2 = wr[(kk + 2) * HH], w3 = wr[(kk + 3) * HH];
            float4 s;
            s = *(const float4*)&sst[0][k0 + kk]; a0 += s.x * w0 + s.y * w1 + s.z * w2 + s.w * w3;
            s = *(const float4*)&sst[1][k0 + kk]; a1 += s.x * w0 + s.y * w1 + s.z * w2 + s.w * w3;
            s = *(const float4*)&sst[2][k0 + kk]; a2 += s.x * w0 + s.y * w1 + s.z * w2 + s.w * w3;
            s = *(const float4*)&sst[3][k0 + kk]; a3 += s.x * w0 + s.y * w1 + s.z * w2 + s.w * w3;
        }
        sred[0][g][t] = a0; sred[1][g][t] = a1; sred[2][g][t] = a2; sred[3][g][t] = a3;
    }
    __syncthreads();
    for (int n = 2 * g; n <= 2 * g + 1; ++n)
        ai0[(size_t)(b0 + n) * HH + t] = sred[n][0][t] + sred[n][1][t] + eb1_0[t];
    __syncthreads();
    {
        float a0 = 0, a1 = 0, a2 = 0, a3 = 0;
        const int k0 = g * 64;
        const float* wr = ew1_0 + (size_t)(HH + k0) * HH + t;
        for (int kk = 0; kk < 64; kk += 4) {
            float w0 = wr[(kk + 0) * HH], w1 = wr[(kk + 1) * HH];
            float w2 = wr[(kk + 2) * HH], w3 = wr[(kk + 3) * HH];
            float4 s;
            s = *(const float4*)&sst[0][k0 + kk]; a0 += s.x * w0 + s.y * w1 + s.z * w2 + s.w * w3;
            s = *(const float4*)&sst[1][k0 + kk]; a1 += s.x * w0 + s.y * w1 + s.z * w2 + s.w * w3;
            s = *(const float4*)&sst[2][k0 + kk]; a2 += s.x * w0 + s.y * w1 + s.z * w2 + s.w * w3;
            s = *(const float4*)&sst[3][k0 + kk]; a3 += s.x * w0 + s.y * w1 + s.z * w2 + s.w * w3;
        }
        sred[0][g][t] = a0; sred[1][g][t] = a1; sred[2][g][t] = a2; sred[3][g][t] = a3;
    }
    __syncthreads();
    for (int n = 2 * g; n <= 2 * g + 1; ++n)
        aj0[(size_t)(b0 + n) * HH + t] = sred[n][0][t] + sred[n][1][t];
}

__global__ void k_dist(const float* __restrict__ npos, float* __restrict__ dist) {
    int idx = blockIdx.x * blockDim.x + threadIdx.x;
    if (idx >= BB * NN * NN) return;
    int b = idx / (NN * NN);
    int r = idx % (NN * NN);
    int i = r / NN, j = r % NN;
    float dx = npos[(b * NN + i) * 2 + 0] - npos[(b * NN + j) * 2 + 0];
    float dy = npos[(b * NN + i) * 2 + 1] - npos[(b * NN + j) * 2 + 1];
    dist[idx] = sqrtf(dx * dx + dy * dy + 1e-12f);
}

__global__ __launch_bounds__(256) void k_edge(
    const float* __restrict__ ai, const float* __restrict__ aj,
    const float* __restrict__ dist, const float* __restrict__ mask,
    const float* __restrict__ wd, float* __restrict__ Sp) {
    const int tid = threadIdx.x;
    const int t = tid & 127;
    const int g = tid >> 7;
    const int blk = blockIdx.x;
    const int p = blk >> 2, q = blk & 3;
    const int n0 = p * 2, n1 = p * 2 + 1;
    const int b = n0 / NN;
    const int jb = q * 96;

    __shared__ __align__(16) float4 sdm[96];
    __shared__ float sred[2][2][HH];

    for (int i = tid; i < 96; i += 256) {
        int j = jb + i;
        sdm[i] = make_float4(dist[(size_t)n0 * NN + j], dist[(size_t)n1 * NN + j],
                             mask[b * NN + j], 0.0f);
    }
    const float av0 = ai[(size_t)n0 * HH + t];
    const float av1 = ai[(size_t)n1 * HH + t];
    const float wdt = wd[t];
    __syncthreads();

    const float* pa = aj + ((size_t)b * NN + jb) * HH + t;
    float acc0 = 0.0f, acc1 = 0.0f;
    #pragma unroll 4
    for (int i = g; i < 96; i += 2) {
        float4 dm = sdm[i];
        float a = pa[(size_t)i * HH];
        float v0 = av0 + a + dm.x * wdt;
        float v1 = av1 + a + dm.y * wdt;
        acc0 = fmaf(dm.z, silu_f(v0), acc0);
        acc1 = fmaf(dm.z, silu_f(v1), acc1);
    }
    sred[0][g][t] = acc0;
    sred[1][g][t] = acc1;
    __syncthreads();
    if (g == 0) Sp[((size_t)q * TOTN + n0) * HH + t] = sred[0][0][t] + sred[0][1][t];
    else        Sp[((size_t)q * TOTN + n1) * HH + t] = sred[1][0][t] + sred[1][1][t];
}

template<bool LAST>
__global__ __launch_bounds__(512) void k_nodeup(
    const float* __restrict__ Sp, float* __restrict__ state,
    const float* __restrict__ mask, const float* __restrict__ scal,
    const float* __restrict__ ew2, const float* __restrict__ eb2,
    const float* __restrict__ nw1, const float* __restrict__ nb1,
    const float* __restrict__ nw2, const float* __restrict__ nb2,
    const float* __restrict__ ew1n, const float* __restrict__ eb1n,
    float* __restrict__ ai_out, float* __restrict__ aj_out,
    const float* __restrict__ fnoise, const float* __restrict__ pnoise,
    const float* __restrict__ fw1, const float* __restrict__ fb1,
    const float* __restrict__ fw2, const float* __restrict__ fb2,
    const float* __restrict__ pw1, const float* __restrict__ pb1,
    const float* __restrict__ pw2, const float* __restrict__ pb2,
    float* __restrict__ accums, float* __restrict__ gembp) {
    const int tid = threadIdx.x;
    const int t = tid & 127;
    const int g = tid >> 7;
    const int b0 = blockIdx.x * 2;
    const int b = b0 / NN;

    __shared__ __align__(16) float sS[2][HH];
    __shared__ __align__(16) float sst[2][HH];
    __shared__ __align__(16) float sagg[2][HH];
    __shared__ __align__(16) float sh[2][HH];
    __shared__ float sred[2][4][HH];
    __shared__ float lf, lp;

    if (tid < 2 * HH) {
        int n = tid >> 7, tt = tid & 127;
        int gn = b0 + n;
        sS[n][tt] = Sp[((size_t)0 * TOTN + gn) * HH + tt] + Sp[((size_t)1 * TOTN + gn) * HH + tt]
                  + Sp[((size_t)2 * TOTN + gn) * HH + tt] + Sp[((size_t)3 * TOTN + gn) * HH + tt];
        sst[n][tt] = state[(size_t)gn * HH + tt];
    }
    if (tid == 0) { lf = 0.0f; lp = 0.0f; }
    __syncthreads();

    {
        float a0 = 0, a1 = 0;
        const int k0 = g * 32;
        const float* wr = ew2 + (size_t)k0 * HH + t;
        for (int kk = 0; kk < 32; kk += 4) {
            float w0 = wr[(kk + 0) * HH], w1 = wr[(kk + 1) * HH];
            float w2 = wr[(kk + 2) * HH], w3 = wr[(kk + 3) * HH];
            float4 s;
            s = *(const float4*)&sS[0][k0 + kk]; a0 += s.x * w0 + s.y * w1 + s.z * w2 + s.w * w3;
            s = *(const float4*)&sS[1][k0 + kk]; a1 += s.x * w0 + s.y * w1 + s.z * w2 + s.w * w3;
        }
        sred[0][g][t] = a0; sred[1][g][t] = a1;
    }
    __syncthreads();
    if (g < 2) {
        const float msum = scal[b * 4 + 2];
        float mi = mask[b0 + g];
        float denom = fmaxf(mi * msum, 1.0f);
        float a = sred[g][0][t] + sred[g][1][t] + sred[g][2][t] + sred[g][3][t] + msum * eb2[t];
        sagg[g][t] = mi * a / denom;
    }
    __syncthreads();

    {
        float a0 = 0, a1 = 0;
        const int r0 = g * 64;
        const float* wr = nw1 + (size_t)r0 * HH + t;
        const float (*inp)[HH] = (g < 2) ? (const float (*)[HH])sst : (const float (*)[HH])sagg;
        const int rb = (g & 1) * 64;
        for (int kk = 0; kk < 64; kk += 4) {
            float w0 = wr[(kk + 0) * HH], w1 = wr[(kk + 1) * HH];
            float w2 = wr[(kk + 2) * HH], w3 = wr[(kk + 3) * HH];
            float4 s;
            s = *(const float4*)&inp[0][rb + kk]; a0 += s.x * w0 + s.y * w1 + s.z * w2 + s.w * w3;
            s = *(const float4*)&inp[1][rb + kk]; a1 += s.x * w0 + s.y * w1 + s.z * w2 + s.w * w3;
        }
        sred[0][g][t] = a0; sred[1][g][t] = a1;
    }
    __syncthreads();
    if (g < 2) sh[g][t] = silu_f(sred[g][0][t] + sred[g][1][t] + sred[g][2][t] + sred[g][3][t] + nb1[t]);
    __syncthreads();

    {
        float a0 = 0, a1 = 0;
        const int k0 = g * 32;
        const float* wr = nw2 + (size_t)k0 * HH + t;
        for (int kk = 0; kk < 32; kk += 4) {
            float w0 = wr[(kk + 0) * HH], w1 = wr[(kk + 1) * HH];
            float w2 = wr[(kk + 2) * HH], w3 = wr[(kk + 3) * HH];
            float4 s;
            s = *(const float4*)&sh[0][k0 + kk]; a0 += s.x * w0 + s.y * w1 + s.z * w2 + s.w * w3;
            s = *(const float4*)&sh[1][k0 + kk]; a1 += s.x * w0 + s.y * w1 + s.z * w2 + s.w * w3;
        }
        sred[0][g][t] = a0; sred[1][g][t] = a1;
    }
    __syncthreads();
    if (g < 2) {
        int gn = b0 + g;
        float mi = mask[gn];
        float ns = sst[g][t] + (sred[g][0][t] + sred[g][1][t] + sred[g][2][t] + sred[g][3][t] + nb2[t]) * mi;
        state[(size_t)gn * HH + t] = ns;
        sst[g][t] = ns;
    }
    __syncthreads();

    if (!LAST) {
        {
            float a0 = 0, a1 = 0;
            const int k0 = g * 32;
            const float* wr = ew1n + (size_t)k0 * HH + t;
            for (int kk = 0; kk < 32; kk += 4) {
                float w0 = wr[(kk + 0) * HH], w1 = wr[(kk + 1) * HH];
                float w2 = wr[(kk + 2) * HH], w3 = wr[(kk + 3) * HH];
                float4 s;
                s = *(const float4*)&sst[0][k0 + kk]; a0 += s.x * w0 + s.y * w1 + s.z * w2 + s.w * w3;
                s = *(const float4*)&sst[1][k0 + kk]; a1 += s.x * w0 + s.y * w1 + s.z * w2 + s.w * w3;
            }
            sred[0][g][t] = a0; sred[1][g][t] = a1;
        }
        __syncthreads();
        if (g < 2) ai_out[(size_t)(b0 + g) * HH + t] =
            sred[g][0][t] + sred[g][1][t] + sred[g][2][t] + sred[g][3][t] + eb1n[t];
        __syncthreads();
        {
            float a0 = 0, a1 = 0;
            const int k0 = g * 32;
            const float* wr = ew1n + (size_t)(HH + k0) * HH + t;
            for (int kk = 0; kk < 32; kk += 4) {
                float w0 = wr[(kk + 0) * HH], w1 = wr[(kk + 1) * HH];
                float w2 = wr[(kk + 2) * HH], w3 = wr[(kk + 3) * HH];
                float4 s;
                s = *(const float4*)&sst[0][k0 + kk]; a0 += s.x * w0 + s.y * w1 + s.z * w2 + s.w * w3;
                s = *(const float4*)&sst[1][k0 + kk]; a1 += s.x * w0 + s.y * w1 + s.z * w2 + s.w * w3;
            }
            sred[0][g][t] = a0; sred[1][g][t] = a1;
        }
        __syncthreads();
        if (g < 2) aj_out[(size_t)(b0 + g) * HH + t] =
            sred[g][0][t] + sred[g][1][t] + sred[g][2][t] + sred[g][3][t];
    } else {
        {
            float a0 = 0, a1 = 0;
            const int k0 = g * 32;
            const float* wr = fw1 + (size_t)k0 * HH + t;
            for (int kk = 0; kk < 32; kk += 4) {
                float w0 = wr[(kk + 0) * HH], w1 = wr[(kk + 1) * HH];
                float w2 = wr[(kk + 2) * HH], w3 = wr[(kk + 3) * HH];
                float4 s;
                s = *(const float4*)&sst[0][k0 + kk]; a0 += s.x * w0 + s.y * w1 + s.z * w2 + s.w * w3;
                s = *(const float4*)&sst[1][k0 + kk]; a1 += s.x * w0 + s.y * w1 + s.z * w2 + s.w * w3;
            }
            sred[0][g][t] = a0; sred[1][g][t] = a1;
        }
        __syncthreads();
        if (g < 2) sS[g][t] = silu_f(sred[g][0][t] + sred[g][1][t] + sred[g][2][t] + sred[g][3][t] + fb1[t]);
        __syncthreads();
        {
            float a0 = 0, a1 = 0;
            const int k0 = g * 32;
            const float* wr = pw1 + (size_t)k0 * HH + t;
            for (int kk = 0; kk < 32; kk += 4) {
                float w0 = wr[(kk + 0) * HH], w1 = wr[(kk + 1) * HH];
                float w2 = wr[(kk + 2) * HH], w3 = wr[(kk + 3) * HH];
                float4 s;
                s = *(const float4*)&sst[0][k0 + kk]; a0 += s.x * w0 + s.y * w1 + s.z * w2 + s.w * w3;
                s = *(const float4*)&sst[1][k0 + kk]; a1 += s.x * w0 + s.y * w1 + s.z * w2 + s.w * w3;
            }
            sred[0][g][t] = a0; sred[1][g][t] = a1;
        }
        __syncthreads();
        if (g < 2) sagg[g][t] = silu_f(sred[g][0][t] + sred[g][1][t] + sred[g][2][t] + sred[g][3][t] + pb1[t]);
        __syncthreads();

        if (tid < 128) {
            int n = tid >> 6, lane = tid & 63;
            int gn = b0 + n;
            float mi = mask[gn];
            if (lane < ND) {
                float o = fb2[lane];
                for (int k = 0; k < HH; ++k) o += sS[n][k] * fw2[k * ND + lane];
                float d = o - fnoise[(size_t)gn * ND + lane];
                atomicAdd(&lf, mi * d * d);
            } else if (lane < ND + 2) {
                int c = lane - ND;
                float o = pb2[c];
                for (int k = 0; k < HH; ++k) o += sagg[n][k] * pw2[k * 2 + c];
                float d = o - pnoise[(size_t)gn * 2 + c];
                atomicAdd(&lp, mi * d * d);
            }
        }
        if (g == 0) {
            float v = sst[0][t] * mask[b0] + sst[1][t] * mask[b0 + 1];
            gembp[(size_t)blockIdx.x * HH + t] = v;
        }
        __syncthreads();
        if (tid == 0) {
            atomicAdd(&accums[0], lf);
            atomicAdd(&accums[1], lp);
        }
    }
}

__global__ __launch_bounds__(256) void k_final(
    const float* __restrict__ gembp, const float* __restrict__ targets,
    const float* __restrict__ pweights,
    const float* __restrict__ w1, const float* __restrict__ b1,
    const float* __restrict__ w2, const float* __restrict__ b2,
    const float* __restrict__ w3, const float* __restrict__ b3,
    const float* __restrict__ accums, const float* __restrict__ scal,
    float* __restrict__ out) {
    const int tid = threadIdx.x;
    const int t = tid & 127;
    const int b = tid >> 7;
    __shared__ float g2[BB][HH], h1[BB][HH], h2[BB][64];
    __shared__ float pl;
    if (tid == 0) pl = 0.0f;

    float acc = 0.0f;
    const float* gp = gembp + (size_t)b * 192 * HH + t;
    #pragma unroll 8
    for (int r = 0; r < 192; ++r) acc += gp[(size_t)r * HH];
    g2[b][t] = acc / fmaxf(scal[b * 4 + 2], 1.0f);
    __syncthreads();

    float a = b1[t];
    for (int k = 0; k < HH; ++k) a += g2[b][k] * w1[k * HH + t];
    h1[b][t] = silu_f(a);
    __syncthreads();
    if (t < 64) {
        float a2 = b2[t];
        for (int k = 0; k < HH; ++k) a2 += h1[b][k] * w2[k * 64 + t];
        h2[b][t] = silu_f(a2);
    }
    __syncthreads();
    if (t < 4) {
        float o = b3[t];
        for (int k = 0; k < 64; ++k) o += h2[b][k] * w3[k * 4 + t];
        float d = o - targets[b * 4 + t];
        atomicAdd(&pl, d * d * pweights[t]);
    }
    __syncthreads();
    if (tid == 0) {
        float msumt = fmaxf(scal[0 * 4 + 2] + scal[1 * 4 + 2], 1.0f);
        float noise = (accums[0] + accums[1]) / msumt;
        float prop = pl / (float)(BB * 4);
        out[0] = noise;
        out[1] = prop;
        out[2] = noise + prop;
    }
}

// ============================================================================
extern "C" void kernel_launch(void* const* d_in, const int* in_sizes, int n_in,
                              void* d_out, int out_size, void* d_ws, size_t ws_size,
                              hipStream_t stream) {
    const float* node_features  = (const float*)d_in[0];
    const float* positions      = (const float*)d_in[1];
    const float* mask           = (const float*)d_in[2];
    const float* condition      = (const float*)d_in[3];
    const float* targets        = (const float*)d_in[4];
    const float* pweights       = (const float*)d_in[5];
    const float* feature_noise  = (const float*)d_in[6];
    const float* position_noise = (const float*)d_in[7];
    const int*   timesteps      = (const int*)d_in[8];
    const float* time_w1 = (const float*)d_in[9];   const float* time_b1 = (const float*)d_in[10];
    const float* time_w2 = (const float*)d_in[11];  const float* time_b2 = (const float*)d_in[12];
    const float* cond_w1 = (const float*)d_in[13];  const float* cond_b1 = (const float*)d_in[14];
    const float* cond_w2 = (const float*)d_in[15];  const float* cond_b2 = (const float*)d_in[16];
    const float* nodep_w1 = (const float*)d_in[17]; const float* nodep_b1 = (const float*)d_in[18];
    const float* nodep_w2 = (const float*)d_in[19]; const float* nodep_b2 = (const float*)d_in[20];
    const float* edge_w1 = (const float*)d_in[21];  const float* edge_b1 = (const float*)d_in[22];
    const float* edge_w2 = (const float*)d_in[23];  const float* edge_b2 = (const float*)d_in[24];
    const float* nodem_w1 = (const float*)d_in[25]; const float* nodem_b1 = (const float*)d_in[26];
    const float* nodem_w2 = (const float*)d_in[27]; const float* nodem_b2 = (const float*)d_in[28];
    const float* feat_w1 = (const float*)d_in[29];  const float* feat_b1 = (const float*)d_in[30];
    const float* feat_w2 = (const float*)d_in[31];  const float* feat_b2 = (const float*)d_in[32];
    const float* pos_w1 = (const float*)d_in[33];   const float* pos_b1 = (const float*)d_in[34];
    const float* pos_w2 = (const float*)d_in[35];   const float* pos_b2 = (const float*)d_in[36];
    const float* prop_w1 = (const float*)d_in[37];  const float* prop_b1 = (const float*)d_in[38];
    const float* prop_w2 = (const float*)d_in[39];  const float* prop_b2 = (const float*)d_in[40];
    const float* prop_w3 = (const float*)d_in[41];  const float* prop_b3 = (const float*)d_in[42];

    float* ws = (float*)d_ws;
    float* outp = (float*)d_out;

    // ---- try PATH A: cooperative mega-kernel ----
    MegaParams P;
    P.node_features = node_features; P.positions = positions; P.mask = mask;
    P.condition = condition; P.targets = targets; P.pweights = pweights;
    P.feature_noise = feature_noise; P.position_noise = position_noise;
    P.timesteps = timesteps;
    P.time_w1 = time_w1; P.time_b1 = time_b1; P.time_w2 = time_w2; P.time_b2 = time_b2;
    P.cond_w1 = cond_w1; P.cond_b1 = cond_b1; P.cond_w2 = cond_w2; P.cond_b2 = cond_b2;
    P.nodep_w1 = nodep_w1; P.nodep_b1 = nodep_b1; P.nodep_w2 = nodep_w2; P.nodep_b2 = nodep_b2;
    P.edge_w1 = edge_w1; P.edge_b1 = edge_b1; P.edge_w2 = edge_w2; P.edge_b2 = edge_b2;
    P.nodem_w1 = nodem_w1; P.nodem_b1 = nodem_b1; P.nodem_w2 = nodem_w2; P.nodem_b2 = nodem_b2;
    P.feat_w1 = feat_w1; P.feat_b1 = feat_b1; P.feat_w2 = feat_w2; P.feat_b2 = feat_b2;
    P.pos_w1 = pos_w1; P.pos_b1 = pos_b1; P.pos_w2 = pos_w2; P.pos_b2 = pos_b2;
    P.prop_w1 = prop_w1; P.prop_b1 = prop_b1; P.prop_w2 = prop_w2; P.prop_b2 = prop_b2;
    P.prop_w3 = prop_w3; P.prop_b3 = prop_b3;
    P.npos   = ws;
    P.ajA    = P.npos + TOTN * 2;
    P.ajB    = P.ajA + TOTN * HH;
    P.gembp  = P.ajB + TOTN * HH;
    P.gemb   = P.gembp + TOTN * HH;
    P.accums = P.gemb + BB * HH;
    P.out    = outp;

    void* args[] = { &P };
    hipError_t err = hipLaunchCooperativeKernel((const void*)k_mega, dim3(TOTN / 2), dim3(256),
                                                args, 0, stream);
    if (err == hipSuccess) return;

    // ---- PATH B fallback: round-8 multi-kernel (measured correct) ----
    float* fb     = P.accums + 4;                 // fallback region after mega's buffers
    float* npos   = fb;                           // 768*2
    float* state  = npos + TOTN * 2;              // 768*128
    float* dist   = state + TOTN * HH;            // 768*384
    float* aiA    = dist + (size_t)TOTN * NN;
    float* ajA    = aiA + TOTN * HH;
    float* aiB    = ajA + TOTN * HH;
    float* ajB    = aiB + TOTN * HH;
    float* Sp     = ajB + TOTN * HH;              // 4*768*128
    float* tc     = Sp + 4 * TOTN * HH;
    float* scal   = tc + BB * HH;
    float* accums = scal + BB * 4;
    float* gembp  = accums + 2;                   // 384*128

    k_prep<<<BB, HH, 0, stream>>>(mask, condition, timesteps,
                                  time_w1, time_b1, time_w2, time_b2,
                                  cond_w1, cond_b1, cond_w2, cond_b2,
                                  tc, scal, accums);
    k_node_init<<<TOTN / 4, 256, 0, stream>>>(node_features, positions, feature_noise, position_noise,
                                              nodep_w1, nodep_b1, nodep_w2, nodep_b2,
                                              tc, scal, edge_w1, edge_b1, state, npos, aiA, ajA);
    k_dist<<<(BB * NN * NN + 255) / 256, 256, 0, stream>>>(npos, dist);

    for (int l = 0; l < LL; ++l) {
        const float* ew1l = edge_w1 + (size_t)l * (2 * HH + 1) * HH;
        const float* wd   = ew1l + (size_t)(2 * HH) * HH;
        const float* ew2  = edge_w2 + (size_t)l * HH * HH;
        const float* eb2  = edge_b2 + (size_t)l * HH;
        const float* nw1  = nodem_w1 + (size_t)l * 2 * HH * HH;
        const float* nb1  = nodem_b1 + (size_t)l * HH;
        const float* nw2  = nodem_w2 + (size_t)l * HH * HH;
        const float* nb2  = nodem_b2 + (size_t)l * HH;
        const float* ew1n = edge_w1 + (size_t)(l + 1) * (2 * HH + 1) * HH;
        const float* eb1n = edge_b1 + (size_t)(l + 1) * HH;

        const float* ai_in = (l & 1) ? aiB : aiA;
        const float* aj_in = (l & 1) ? ajB : ajA;
        float* ai_out = (l & 1) ? aiA : aiB;
        float* aj_out = (l & 1) ? ajA : ajB;

        k_edge<<<TOTN / 2 * 4, 256, 0, stream>>>(ai_in, aj_in, dist, mask, wd, Sp);

        if (l < LL - 1) {
            k_nodeup<false><<<TOTN / 2, 512, 0, stream>>>(
                Sp, state, mask, scal, ew2, eb2, nw1, nb1, nw2, nb2, ew1n, eb1n,
                ai_out, aj_out,
                feature_noise, position_noise, feat_w1, feat_b1, feat_w2, feat_b2,
                pos_w1, pos_b1, pos_w2, pos_b2, accums, gembp);
        } else {
            k_nodeup<true><<<TOTN / 2, 512, 0, stream>>>(
                Sp, state, mask, scal, ew2, eb2, nw1, nb1, nw2, nb2, ew1n, eb1n,
                ai_out, aj_out,
                feature_noise, position_noise, feat_w1, feat_b1, feat_w2, feat_b2,
                pos_w1, pos_b1, pos_w2, pos_b2, accums, gembp);
        }
    }

    k_final<<<1, 256, 0, stream>>>(gembp, targets, pweights,
                                   prop_w1, prop_b1, prop_w2, prop_b2, prop_w3, prop_b3,
                                   accums, scal, outp);
}

// Round 16
// 334.051 us; speedup vs baseline: 2.0874x; 2.0874x over previous
//
#include <hip/hip_runtime.h>
#include <math.h>

#define BB 2
#define NN 384
#define ND 8
#define CD 16
#define HH 128
#define LL 4
#define TT 100
#define TOTN (BB * NN)   // 768

__device__ __forceinline__ float silu_f(float x) {
    float s = 1.0f / (1.0f + __expf(-x));
    return x * s;
}

// ---------------- per-batch prep ----------------
__global__ void k_prep(const float* __restrict__ mask, const float* __restrict__ condition,
                       const int* __restrict__ timesteps,
                       const float* __restrict__ time_w1, const float* __restrict__ time_b1,
                       const float* __restrict__ time_w2, const float* __restrict__ time_b2,
                       const float* __restrict__ cond_w1, const float* __restrict__ cond_b1,
                       const float* __restrict__ cond_w2, const float* __restrict__ cond_b2,
                       float* __restrict__ tc, float* __restrict__ scal, float* __restrict__ accums) {
    int b = blockIdx.x;
    int t = threadIdx.x;
    __shared__ float sh[HH];
    __shared__ float sh2[HH];
    __shared__ float shc[CD];
    __shared__ float red[HH];

    if (b == 0 && t < 2) accums[t] = 0.0f;

    int ts = timesteps[b];
    float ab = 1.0f;
    for (int k = 0; k <= ts; ++k) {
        float beta = 1e-4f + (0.02f - 1e-4f) * ((float)k / (float)(TT - 1));
        ab *= (1.0f - beta);
    }
    if (t == 0) {
        scal[b * 4 + 0] = sqrtf(ab);
        scal[b * 4 + 1] = sqrtf(1.0f - ab);
    }
    float m = 0.0f;
    for (int j = t; j < NN; j += HH) m += mask[b * NN + j];
    red[t] = m;
    __syncthreads();
    for (int s = 64; s > 0; s >>= 1) {
        if (t < s) red[t] += red[t + s];
        __syncthreads();
    }
    if (t == 0) scal[b * 4 + 2] = red[0];

    const int half = HH / 2;
    float factor = logf(10000.0f) / (float)(half - 1);
    float tf = (float)ts;
    float temb;
    if (t < half) temb = sinf(tf * __expf(-factor * (float)t));
    else          temb = cosf(tf * __expf(-factor * (float)(t - half)));
    sh[t] = temb;
    if (t < CD) shc[t] = condition[b * CD + t];
    __syncthreads();

    float acc = time_b1[t];
    for (int k = 0; k < HH; ++k) acc += sh[k] * time_w1[k * HH + t];
    sh2[t] = silu_f(acc);
    __syncthreads();
    float acc2 = time_b2[t];
    for (int k = 0; k < HH; ++k) acc2 += sh2[k] * time_w2[k * HH + t];
    float acc3 = cond_b1[t];
    for (int k = 0; k < CD; ++k) acc3 += shc[k] * cond_w1[k * HH + t];
    __syncthreads();
    sh[t] = silu_f(acc3);
    __syncthreads();
    float acc4 = cond_b2[t];
    for (int k = 0; k < HH; ++k) acc4 += sh[k] * cond_w2[k * HH + t];

    tc[b * HH + t] = acc2 + acc4;
}

// ---------------- node init: 4 nodes/block ----------------
__global__ __launch_bounds__(256) void k_node_init(
    const float* __restrict__ node_features, const float* __restrict__ positions,
    const float* __restrict__ feature_noise, const float* __restrict__ position_noise,
    const float* __restrict__ nodep_w1, const float* __restrict__ nodep_b1,
    const float* __restrict__ nodep_w2, const float* __restrict__ nodep_b2,
    const float* __restrict__ tc, const float* __restrict__ scal,
    const float* __restrict__ ew1_0, const float* __restrict__ eb1_0,
    float* __restrict__ state, float* __restrict__ npos,
    float* __restrict__ ai0, float* __restrict__ aj0) {
    const int tid = threadIdx.x;
    const int t = tid & 127;
    const int g = tid >> 7;
    const int b0 = blockIdx.x * 4;
    const int b = b0 / NN;

    __shared__ __align__(16) float x[4][12];
    __shared__ __align__(16) float sh1[4][HH];
    __shared__ __align__(16) float sst[4][HH];
    __shared__ float sred[4][2][HH];

    if (tid < 40) {
        int n = tid / 10, c = tid % 10;
        int gn = b0 + n;
        float sab = scal[b * 4 + 0], s1ab = scal[b * 4 + 1];
        float v;
        if (c < ND) {
            v = sab * node_features[gn * ND + c] + s1ab * feature_noise[gn * ND + c];
        } else {
            int d = c - ND;
            v = sab * positions[gn * 2 + d] + s1ab * position_noise[gn * 2 + d];
            npos[gn * 2 + d] = v;
        }
        x[n][c] = v;
    }
    __syncthreads();

    for (int n = 2 * g; n <= 2 * g + 1; ++n) {
        float a = nodep_b1[t];
        #pragma unroll
        for (int k = 0; k < ND + 2; ++k) a += x[n][k] * nodep_w1[k * HH + t];
        sh1[n][t] = silu_f(a);
    }
    __syncthreads();

    {
        float a0 = 0, a1 = 0, a2 = 0, a3 = 0;
        const int k0 = g * 64;
        const float* wr = nodep_w2 + (size_t)k0 * HH + t;
        for (int kk = 0; kk < 64; kk += 4) {
            float w0 = wr[(kk + 0) * HH], w1 = wr[(kk + 1) * HH];
            float w2 = wr[(kk + 2) * HH], w3 = wr[(kk + 3) * HH];
            float4 s;
            s = *(const float4*)&sh1[0][k0 + kk]; a0 += s.x * w0 + s.y * w1 + s.z * w2 + s.w * w3;
            s = *(const float4*)&sh1[1][k0 + kk]; a1 += s.x * w0 + s.y * w1 + s.z * w2 + s.w * w3;
            s = *(const float4*)&sh1[2][k0 + kk]; a2 += s.x * w0 + s.y * w1 + s.z * w2 + s.w * w3;
            s = *(const float4*)&sh1[3][k0 + kk]; a3 += s.x * w0 + s.y * w1 + s.z * w2 + s.w * w3;
        }
        sred[0][g][t] = a0; sred[1][g][t] = a1; sred[2][g][t] = a2; sred[3][g][t] = a3;
    }
    __syncthreads();
    {
        float tcv = nodep_b2[t] + tc[b * HH + t];
        for (int n = 2 * g; n <= 2 * g + 1; ++n) {
            float st = sred[n][0][t] + sred[n][1][t] + tcv;
            state[(size_t)(b0 + n) * HH + t] = st;
            sst[n][t] = st;
        }
    }
    __syncthreads();

    {
        float a0 = 0, a1 = 0, a2 = 0, a3 = 0;
        const int k0 = g * 64;
        const float* wr = ew1_0 + (size_t)k0 * HH + t;
        for (int kk = 0; kk < 64; kk += 4) {
            float w0 = wr[(kk + 0) * HH], w1 = wr[(kk + 1) * HH];
            float w2 = wr[(kk + 2) * HH], w3 = wr[(kk + 3) * HH];
            float4 s;
            s = *(const float4*)&sst[0][k0 + kk]; a0 += s.x * w0 + s.y * w1 + s.z * w2 + s.w * w3;
            s = *(const float4*)&sst[1][k0 + kk]; a1 += s.x * w0 + s.y * w1 + s.z * w2 + s.w * w3;
            s = *(const float4*)&sst[2][k0 + kk]; a2 += s.x * w0 + s.y * w1 + s.z * w2 + s.w * w3;
            s = *(const float4*)&sst[3][k0 + kk]; a3 += s.x * w0 + s.y * w1 + s.z * w2 + s.w * w3;
        }
        sred[0][g][t] = a0; sred[1][g][t] = a1; sred[2][g][t] = a2; sred[3][g][t] = a3;
    }
    __syncthreads();
    for (int n = 2 * g; n <= 2 * g + 1; ++n)
        ai0[(size_t)(b0 + n) * HH + t] = sred[n][0][t] + sred[n][1][t] + eb1_0[t];
    __syncthreads();
    {
        float a0 = 0, a1 = 0, a2 = 0, a3 = 0;
        const int k0 = g * 64;
        const float* wr = ew1_0 + (size_t)(HH + k0) * HH + t;
        for (int kk = 0; kk < 64; kk += 4) {
            float w0 = wr[(kk + 0) * HH], w1 = wr[(kk + 1) * HH];
            float w2 = wr[(kk + 2) * HH], w3 = wr[(kk + 3) * HH];
            float4 s;
            s = *(const float4*)&sst[0][k0 + kk]; a0 += s.x * w0 + s.y * w1 + s.z * w2 + s.w * w3;
            s = *(const float4*)&sst[1][k0 + kk]; a1 += s.x * w0 + s.y * w1 + s.z * w2 + s.w * w3;
            s = *(const float4*)&sst[2][k0 + kk]; a2 += s.x * w0 + s.y * w1 + s.z * w2 + s.w * w3;
            s = *(const float4*)&sst[3][k0 + kk]; a3 += s.x * w0 + s.y * w1 + s.z * w2 + s.w * w3;
        }
        sred[0][g][t] = a0; sred[1][g][t] = a1; sred[2][g][t] = a2; sred[3][g][t] = a3;
    }
    __syncthreads();
    for (int n = 2 * g; n <= 2 * g + 1; ++n)
        aj0[(size_t)(b0 + n) * HH + t] = sred[n][0][t] + sred[n][1][t];
}

// ---------------- pairwise distances ----------------
__global__ void k_dist(const float* __restrict__ npos, float* __restrict__ dist) {
    int idx = blockIdx.x * blockDim.x + threadIdx.x;
    if (idx >= BB * NN * NN) return;
    int b = idx / (NN * NN);
    int r = idx % (NN * NN);
    int i = r / NN, j = r % NN;
    float dx = npos[(b * NN + i) * 2 + 0] - npos[(b * NN + j) * 2 + 0];
    float dy = npos[(b * NN + i) * 2 + 1] - npos[(b * NN + j) * 2 + 1];
    dist[idx] = sqrtf(dx * dx + dy * dy + 1e-12f);
}

// ---------------- fused layer: edge sum + agg + node MLP + update + next proj | heads ----------------
// 384 blocks x 512 threads; block owns nodes {2p,2p+1}; q = tid>>7 in 0..3
template<bool LAST>
__global__ __launch_bounds__(512) void k_layer2(
    const float* __restrict__ ai_io_in, float* __restrict__ ai_io_out,
    const float* __restrict__ aj_in, float* __restrict__ aj_out,
    const float* __restrict__ dist, const float* __restrict__ mask,
    const float* __restrict__ scal, float* __restrict__ state,
    const float* __restrict__ wd,
    const float* __restrict__ ew2, const float* __restrict__ eb2,
    const float* __restrict__ nw1, const float* __restrict__ nb1,
    const float* __restrict__ nw2, const float* __restrict__ nb2,
    const float* __restrict__ ew1n, const float* __restrict__ eb1n,
    const float* __restrict__ fnoise, const float* __restrict__ pnoise,
    const float* __restrict__ fw1, const float* __restrict__ fb1,
    const float* __restrict__ fw2, const float* __restrict__ fb2,
    const float* __restrict__ pw1, const float* __restrict__ pb1,
    const float* __restrict__ pw2, const float* __restrict__ pb2,
    float* __restrict__ accums, float* __restrict__ gembp) {
    const int tid = threadIdx.x;
    const int t = tid & 127;
    const int q = tid >> 7;          // 0..3
    const int n0 = blockIdx.x * 2;
    const int b = n0 / NN;

    __shared__ float s_d[2][NN];                       // 3 KB
    __shared__ float s_m[NN];                          // 1.5 KB
    __shared__ __align__(16) float s_S[2][HH];
    __shared__ __align__(16) float s_st[2][HH];
    __shared__ __align__(16) float s_agg[2][HH];
    __shared__ __align__(16) float s_h[2][HH];
    __shared__ float s_red[2][4][HH];                  // 4 KB
    __shared__ float lf, lp;

    // stage dist rows + mask + state
    for (int i = tid; i < NN; i += 512) {
        s_d[0][i] = dist[(size_t)n0 * NN + i];
        s_d[1][i] = dist[(size_t)(n0 + 1) * NN + i];
        s_m[i] = mask[b * NN + i];
    }
    if (tid < 2 * HH) {
        int n = tid >> 7, tt = tid & 127;
        s_st[n][tt] = state[(size_t)(n0 + n) * HH + tt];
    }
    if (tid == 0) { lf = 0.0f; lp = 0.0f; }
    const float av0 = ai_io_in[(size_t)n0 * HH + t];
    const float av1 = ai_io_in[(size_t)(n0 + 1) * HH + t];
    const float wdt = wd[t];
    __syncthreads();

    // ---- edge: q-group covers 96 j's, 2-node aj reuse ----
    {
        float acc0 = 0.0f, acc1 = 0.0f;
        const int jb = q * 96;
        const float* pa = aj_in + ((size_t)b * NN + jb) * HH + t;
        #pragma unroll 4
        for (int i = 0; i < 96; ++i) {
            float a = pa[(size_t)i * HH];
            int j = jb + i;
            float m = s_m[j];
            acc0 = fmaf(m, silu_f(av0 + a + s_d[0][j] * wdt), acc0);
            acc1 = fmaf(m, silu_f(av1 + a + s_d[1][j] * wdt), acc1);
        }
        s_red[0][q][t] = acc0;
        s_red[1][q][t] = acc1;
    }
    __syncthreads();
    if (q < 2) s_S[q][t] = s_red[q][0][t] + s_red[q][1][t] + s_red[q][2][t] + s_red[q][3][t];
    __syncthreads();

    // ---- agg = mi*(S@ew2 + msum*eb2)/denom (4-way k-split) ----
    {
        float a0 = 0, a1 = 0;
        const int k0 = q * 32;
        const float* wr = ew2 + (size_t)k0 * HH + t;
        for (int kk = 0; kk < 32; kk += 4) {
            float w0 = wr[(kk + 0) * HH], w1 = wr[(kk + 1) * HH];
            float w2 = wr[(kk + 2) * HH], w3 = wr[(kk + 3) * HH];
            float4 s;
            s = *(const float4*)&s_S[0][k0 + kk]; a0 += s.x * w0 + s.y * w1 + s.z * w2 + s.w * w3;
            s = *(const float4*)&s_S[1][k0 + kk]; a1 += s.x * w0 + s.y * w1 + s.z * w2 + s.w * w3;
        }
        s_red[0][q][t] = a0; s_red[1][q][t] = a1;
    }
    __syncthreads();
    if (q < 2) {
        const float msum = scal[b * 4 + 2];
        float mi = s_m[(n0 + q) - b * NN];
        float denom = fmaxf(mi * msum, 1.0f);
        float a = s_red[q][0][t] + s_red[q][1][t] + s_red[q][2][t] + s_red[q][3][t] + msum * eb2[t];
        s_agg[q][t] = mi * a / denom;
    }
    __syncthreads();

    // ---- h = silu([st, agg] @ nw1 + nb1) (4-way row-split) ----
    {
        float a0 = 0, a1 = 0;
        const int r0 = q * 64;
        const float* wr = nw1 + (size_t)r0 * HH + t;
        const float (*inp)[HH] = (q < 2) ? (const float (*)[HH])s_st : (const float (*)[HH])s_agg;
        const int rb = (q & 1) * 64;
        for (int kk = 0; kk < 64; kk += 4) {
            float w0 = wr[(kk + 0) * HH], w1 = wr[(kk + 1) * HH];
            float w2 = wr[(kk + 2) * HH], w3 = wr[(kk + 3) * HH];
            float4 s;
            s = *(const float4*)&inp[0][rb + kk]; a0 += s.x * w0 + s.y * w1 + s.z * w2 + s.w * w3;
            s = *(const float4*)&inp[1][rb + kk]; a1 += s.x * w0 + s.y * w1 + s.z * w2 + s.w * w3;
        }
        s_red[0][q][t] = a0; s_red[1][q][t] = a1;
    }
    __syncthreads();
    if (q < 2) s_h[q][t] = silu_f(s_red[q][0][t] + s_red[q][1][t] + s_red[q][2][t] + s_red[q][3][t] + nb1[t]);
    __syncthreads();

    // ---- st += (h@nw2 + nb2)*mi ----
    {
        float a0 = 0, a1 = 0;
        const int k0 = q * 32;
        const float* wr = nw2 + (size_t)k0 * HH + t;
        for (int kk = 0; kk < 32; kk += 4) {
            float w0 = wr[(kk + 0) * HH], w1 = wr[(kk + 1) * HH];
            float w2 = wr[(kk + 2) * HH], w3 = wr[(kk + 3) * HH];
            float4 s;
            s = *(const float4*)&s_h[0][k0 + kk]; a0 += s.x * w0 + s.y * w1 + s.z * w2 + s.w * w3;
            s = *(const float4*)&s_h[1][k0 + kk]; a1 += s.x * w0 + s.y * w1 + s.z * w2 + s.w * w3;
        }
        s_red[0][q][t] = a0; s_red[1][q][t] = a1;
    }
    __syncthreads();
    if (q < 2) {
        int gn = n0 + q;
        float mi = s_m[gn - b * NN];
        float ns = s_st[q][t] + (s_red[q][0][t] + s_red[q][1][t] + s_red[q][2][t] + s_red[q][3][t] + nb2[t]) * mi;
        state[(size_t)gn * HH + t] = ns;
        s_st[q][t] = ns;
    }
    __syncthreads();

    if (!LAST) {
        // ai' (k-split)
        {
            float a0 = 0, a1 = 0;
            const int k0 = q * 32;
            const float* wr = ew1n + (size_t)k0 * HH + t;
            for (int kk = 0; kk < 32; kk += 4) {
                float w0 = wr[(kk + 0) * HH], w1 = wr[(kk + 1) * HH];
                float w2 = wr[(kk + 2) * HH], w3 = wr[(kk + 3) * HH];
                float4 s;
                s = *(const float4*)&s_st[0][k0 + kk]; a0 += s.x * w0 + s.y * w1 + s.z * w2 + s.w * w3;
                s = *(const float4*)&s_st[1][k0 + kk]; a1 += s.x * w0 + s.y * w1 + s.z * w2 + s.w * w3;
            }
            s_red[0][q][t] = a0; s_red[1][q][t] = a1;
        }
        __syncthreads();
        if (q < 2) ai_io_out[(size_t)(n0 + q) * HH + t] =
            s_red[q][0][t] + s_red[q][1][t] + s_red[q][2][t] + s_red[q][3][t] + eb1n[t];
        __syncthreads();
        // aj' (k-split)
        {
            float a0 = 0, a1 = 0;
            const int k0 = q * 32;
            const float* wr = ew1n + (size_t)(HH + k0) * HH + t;
            for (int kk = 0; kk < 32; kk += 4) {
                float w0 = wr[(kk + 0) * HH], w1 = wr[(kk + 1) * HH];
                float w2 = wr[(kk + 2) * HH], w3 = wr[(kk + 3) * HH];
                float4 s;
                s = *(const float4*)&s_st[0][k0 + kk]; a0 += s.x * w0 + s.y * w1 + s.z * w2 + s.w * w3;
                s = *(const float4*)&s_st[1][k0 + kk]; a1 += s.x * w0 + s.y * w1 + s.z * w2 + s.w * w3;
            }
            s_red[0][q][t] = a0; s_red[1][q][t] = a1;
        }
        __syncthreads();
        if (q < 2) aj_out[(size_t)(n0 + q) * HH + t] =
            s_red[q][0][t] + s_red[q][1][t] + s_red[q][2][t] + s_red[q][3][t];
    } else {
        // heads
        {
            float a0 = 0, a1 = 0;
            const int k0 = q * 32;
            const float* wr = fw1 + (size_t)k0 * HH + t;
            for (int kk = 0; kk < 32; kk += 4) {
                float w0 = wr[(kk + 0) * HH], w1 = wr[(kk + 1) * HH];
                float w2 = wr[(kk + 2) * HH], w3 = wr[(kk + 3) * HH];
                float4 s;
                s = *(const float4*)&s_st[0][k0 + kk]; a0 += s.x * w0 + s.y * w1 + s.z * w2 + s.w * w3;
                s = *(const float4*)&s_st[1][k0 + kk]; a1 += s.x * w0 + s.y * w1 + s.z * w2 + s.w * w3;
            }
            s_red[0][q][t] = a0; s_red[1][q][t] = a1;
        }
        __syncthreads();
        if (q < 2) s_S[q][t] = silu_f(s_red[q][0][t] + s_red[q][1][t] + s_red[q][2][t] + s_red[q][3][t] + fb1[t]);
        __syncthreads();
        {
            float a0 = 0, a1 = 0;
            const int k0 = q * 32;
            const float* wr = pw1 + (size_t)k0 * HH + t;
            for (int kk = 0; kk < 32; kk += 4) {
                float w0 = wr[(kk + 0) * HH], w1 = wr[(kk + 1) * HH];
                float w2 = wr[(kk + 2) * HH], w3 = wr[(kk + 3) * HH];
                float4 s;
                s = *(const float4*)&s_st[0][k0 + kk]; a0 += s.x * w0 + s.y * w1 + s.z * w2 + s.w * w3;
                s = *(const float4*)&s_st[1][k0 + kk]; a1 += s.x * w0 + s.y * w1 + s.z * w2 + s.w * w3;
            }
            s_red[0][q][t] = a0; s_red[1][q][t] = a1;
        }
        __syncthreads();
        if (q < 2) s_agg[q][t] = silu_f(s_red[q][0][t] + s_red[q][1][t] + s_red[q][2][t] + s_red[q][3][t] + pb1[t]);
        __syncthreads();

        if (tid < 128) {
            int n = tid >> 6, lane = tid & 63;
            int gn = n0 + n;
            float mi = s_m[gn - b * NN];
            if (lane < ND) {
                float o = fb2[lane];
                for (int k = 0; k < HH; ++k) o += s_S[n][k] * fw2[k * ND + lane];
                float d = o - fnoise[(size_t)gn * ND + lane];
                atomicAdd(&lf, mi * d * d);
            } else if (lane < ND + 2) {
                int c = lane - ND;
                float o = pb2[c];
                for (int k = 0; k < HH; ++k) o += s_agg[n][k] * pw2[k * 2 + c];
                float d = o - pnoise[(size_t)gn * 2 + c];
                atomicAdd(&lp, mi * d * d);
            }
        }
        if (q == 0) {
            float v = s_st[0][t] * s_m[n0 - b * NN] + s_st[1][t] * s_m[n0 + 1 - b * NN];
            gembp[(size_t)blockIdx.x * HH + t] = v;
        }
        __syncthreads();
        if (tid == 0) {
            atomicAdd(&accums[0], lf);
            atomicAdd(&accums[1], lp);
        }
    }
}

// ---------------- final ----------------
__global__ __launch_bounds__(256) void k_final(
    const float* __restrict__ gembp, const float* __restrict__ targets,
    const float* __restrict__ pweights,
    const float* __restrict__ w1, const float* __restrict__ b1,
    const float* __restrict__ w2, const float* __restrict__ b2,
    const float* __restrict__ w3, const float* __restrict__ b3,
    const float* __restrict__ accums, const float* __restrict__ scal,
    float* __restrict__ out) {
    const int tid = threadIdx.x;
    const int t = tid & 127;
    const int b = tid >> 7;
    __shared__ float g2[BB][HH], h1[BB][HH], h2[BB][64];
    __shared__ float pl;
    if (tid == 0) pl = 0.0f;

    float acc = 0.0f;
    const float* gp = gembp + (size_t)b * 192 * HH + t;
    #pragma unroll 8
    for (int r = 0; r < 192; ++r) acc += gp[(size_t)r * HH];
    g2[b][t] = acc / fmaxf(scal[b * 4 + 2], 1.0f);
    __syncthreads();

    float a = b1[t];
    for (int k = 0; k < HH; ++k) a += g2[b][k] * w1[k * HH + t];
    h1[b][t] = silu_f(a);
    __syncthreads();
    if (t < 64) {
        float a2 = b2[t];
        for (int k = 0; k < HH; ++k) a2 += h1[b][k] * w2[k * 64 + t];
        h2[b][t] = silu_f(a2);
    }
    __syncthreads();
    if (t < 4) {
        float o = b3[t];
        for (int k = 0; k < 64; ++k) o += h2[b][k] * w3[k * 4 + t];
        float d = o - targets[b * 4 + t];
        atomicAdd(&pl, d * d * pweights[t]);
    }
    __syncthreads();
    if (tid == 0) {
        float msumt = fmaxf(scal[0 * 4 + 2] + scal[1 * 4 + 2], 1.0f);
        float noise = (accums[0] + accums[1]) / msumt;
        float prop = pl / (float)(BB * 4);
        out[0] = noise;
        out[1] = prop;
        out[2] = noise + prop;
    }
}

extern "C" void kernel_launch(void* const* d_in, const int* in_sizes, int n_in,
                              void* d_out, int out_size, void* d_ws, size_t ws_size,
                              hipStream_t stream) {
    const float* node_features  = (const float*)d_in[0];
    const float* positions      = (const float*)d_in[1];
    const float* mask           = (const float*)d_in[2];
    const float* condition      = (const float*)d_in[3];
    const float* targets        = (const float*)d_in[4];
    const float* pweights       = (const float*)d_in[5];
    const float* feature_noise  = (const float*)d_in[6];
    const float* position_noise = (const float*)d_in[7];
    const int*   timesteps      = (const int*)d_in[8];
    const float* time_w1 = (const float*)d_in[9];   const float* time_b1 = (const float*)d_in[10];
    const float* time_w2 = (const float*)d_in[11];  const float* time_b2 = (const float*)d_in[12];
    const float* cond_w1 = (const float*)d_in[13];  const float* cond_b1 = (const float*)d_in[14];
    const float* cond_w2 = (const float*)d_in[15];  const float* cond_b2 = (const float*)d_in[16];
    const float* nodep_w1 = (const float*)d_in[17]; const float* nodep_b1 = (const float*)d_in[18];
    const float* nodep_w2 = (const float*)d_in[19]; const float* nodep_b2 = (const float*)d_in[20];
    const float* edge_w1 = (const float*)d_in[21];  const float* edge_b1 = (const float*)d_in[22];
    const float* edge_w2 = (const float*)d_in[23];  const float* edge_b2 = (const float*)d_in[24];
    const float* nodem_w1 = (const float*)d_in[25]; const float* nodem_b1 = (const float*)d_in[26];
    const float* nodem_w2 = (const float*)d_in[27]; const float* nodem_b2 = (const float*)d_in[28];
    const float* feat_w1 = (const float*)d_in[29];  const float* feat_b1 = (const float*)d_in[30];
    const float* feat_w2 = (const float*)d_in[31];  const float* feat_b2 = (const float*)d_in[32];
    const float* pos_w1 = (const float*)d_in[33];   const float* pos_b1 = (const float*)d_in[34];
    const float* pos_w2 = (const float*)d_in[35];   const float* pos_b2 = (const float*)d_in[36];
    const float* prop_w1 = (const float*)d_in[37];  const float* prop_b1 = (const float*)d_in[38];
    const float* prop_w2 = (const float*)d_in[39];  const float* prop_b2 = (const float*)d_in[40];
    const float* prop_w3 = (const float*)d_in[41];  const float* prop_b3 = (const float*)d_in[42];

    float* ws = (float*)d_ws;
    float* npos   = ws;                          // 768*2
    float* state  = npos + TOTN * 2;             // 768*128
    float* dist   = state + TOTN * HH;           // 768*384
    float* aiA    = dist + (size_t)TOTN * NN;    // 768*128
    float* aiB    = aiA + TOTN * HH;             // 768*128
    float* ajA    = aiB + TOTN * HH;
    float* ajB    = ajA + TOTN * HH;
    float* tc     = ajB + TOTN * HH;             // B*H
    float* scal   = tc + BB * HH;                // B*4
    float* accums = scal + BB * 4;               // 2
    float* gembp  = accums + 2;                  // 384*128

    float* outp = (float*)d_out;

    k_prep<<<BB, HH, 0, stream>>>(mask, condition, timesteps,
                                  time_w1, time_b1, time_w2, time_b2,
                                  cond_w1, cond_b1, cond_w2, cond_b2,
                                  tc, scal, accums);
    k_node_init<<<TOTN / 4, 256, 0, stream>>>(node_features, positions, feature_noise, position_noise,
                                              nodep_w1, nodep_b1, nodep_w2, nodep_b2,
                                              tc, scal, edge_w1, edge_b1, state, npos, aiA, ajA);
    k_dist<<<(BB * NN * NN + 255) / 256, 256, 0, stream>>>(npos, dist);

    for (int l = 0; l < LL; ++l) {
        const float* ew1l = edge_w1 + (size_t)l * (2 * HH + 1) * HH;
        const float* wd   = ew1l + (size_t)(2 * HH) * HH;
        const float* ew2  = edge_w2 + (size_t)l * HH * HH;
        const float* eb2  = edge_b2 + (size_t)l * HH;
        const float* nw1  = nodem_w1 + (size_t)l * 2 * HH * HH;
        const float* nb1  = nodem_b1 + (size_t)l * HH;
        const float* nw2  = nodem_w2 + (size_t)l * HH * HH;
        const float* nb2  = nodem_b2 + (size_t)l * HH;
        const float* ew1n = edge_w1 + (size_t)(l + 1) * (2 * HH + 1) * HH;
        const float* eb1n = edge_b1 + (size_t)(l + 1) * HH;

        const float* ai_in = (l & 1) ? aiB : aiA;
        float* ai_out      = (l & 1) ? aiA : aiB;
        const float* aj_in = (l & 1) ? ajB : ajA;
        float* aj_out      = (l & 1) ? ajA : ajB;

        if (l < LL - 1) {
            k_layer2<false><<<TOTN / 2, 512, 0, stream>>>(
                ai_in, ai_out, aj_in, aj_out, dist, mask, scal, state, wd,
                ew2, eb2, nw1, nb1, nw2, nb2, ew1n, eb1n,
                feature_noise, position_noise, feat_w1, feat_b1, feat_w2, feat_b2,
                pos_w1, pos_b1, pos_w2, pos_b2, accums, gembp);
        } else {
            k_layer2<true><<<TOTN / 2, 512, 0, stream>>>(
                ai_in, ai_out, aj_in, aj_out, dist, mask, scal, state, wd,
                ew2, eb2, nw1, nb1, nw2, nb2, edge_w1, edge_b1,
                feature_noise, position_noise, feat_w1, feat_b1, feat_w2, feat_b2,
                pos_w1, pos_b1, pos_w2, pos_b2, accums, gembp);
        }
    }

    k_final<<<1, 256, 0, stream>>>(gembp, targets, pweights,
                                   prop_w1, prop_b1, prop_w2, prop_b2, prop_w3, prop_b3,
                                   accums, scal, outp);
}